// Round 3
// baseline (48141.568 us; speedup 1.0000x reference)
//
#include <hip/hip_runtime.h>
#include <cstddef>

#define B_ 64
#define T_ 1024
#define I_ 64
#define H_ 512
#define TC 256                  // time-chunk length
#define NCHUNK (T_ / TC)        // 4
#define MTOT (B_ * T_)          // 65536
#define BH (B_ * H_)            // 32768
#define MC (B_ * TC)            // 16384 rows per chunk GEMM

// ---------------------------------------------------------------------------
// fast tanh: tanh(x) = 1 - 2/(exp2(2*log2e*x)+1). v_exp_f32 + v_rcp_f32,
// ~1e-6 abs error; saturates correctly at +/-1 for large |x|.
// ---------------------------------------------------------------------------
__device__ __forceinline__ float fast_tanh(float x) {
  float e = __builtin_amdgcn_exp2f(2.885390081777927f * x);
  float r = __builtin_amdgcn_rcpf(e + 1.0f);
  return 1.0f - 2.0f * r;
}

// ---------------------------------------------------------------------------
// init: h(-1) -> hbuf parity-1 slots for all 3 layers; zero the flags.
// ---------------------------------------------------------------------------
__global__ __launch_bounds__(256) void init_kernel(const float* __restrict__ hidden,
                                                   float* __restrict__ hbuf,
                                                   unsigned* __restrict__ flags) {
  int idx = blockIdx.x * 256 + threadIdx.x;
  if (idx < 3 * BH) {
    int l = idx / BH, r = idx - l * BH;
    hbuf[(size_t)(l * 2 + 1) * BH + r] = hidden[idx];
  }
  if (idx < 192) flags[idx] = 0u;
}

// ---------------------------------------------------------------------------
// C[m, 0..511] = A[m, :K] @ W[:, :K]^T + bih + bhh.
// A rows: m = b*TC + trel -> A + (m>>8)*bstride + (m&255)*K  (handles both the
// strided original input [B,T_,I] and contiguous chunk buffers [B,TC,H]).
// 128x128 tile, BK=16, 256 threads, 8x8 per thread.  grid = (H/128, MC/128).
// ---------------------------------------------------------------------------
__global__ __launch_bounds__(256) void gemm_xp(const float* __restrict__ A, long bstride, int K,
                                               const float* __restrict__ W,
                                               const float* __restrict__ bih,
                                               const float* __restrict__ bhh,
                                               float* __restrict__ C) {
  __shared__ float As[16][132];
  __shared__ float Ws[16][132];
  const int tid = threadIdx.x;
  const int m0 = blockIdx.y * 128, n0 = blockIdx.x * 128;
  const int tx = tid & 15, ty = tid >> 4;  // n-group, m-group
  float acc[8][8] = {};
  for (int k0 = 0; k0 < K; k0 += 16) {
#pragma unroll
    for (int i = 0; i < 2; i++) {
      int idx = i * 256 + tid;          // float4 slot 0..511
      int r = idx >> 2, kq = (idx & 3) * 4;
      int row = m0 + r;
      const float* ap = A + (long)(row >> 8) * bstride + (long)(row & 255) * K + k0 + kq;
      float4 av = *(const float4*)ap;
      As[kq + 0][r] = av.x; As[kq + 1][r] = av.y; As[kq + 2][r] = av.z; As[kq + 3][r] = av.w;
      const float* wp = W + (long)(n0 + r) * K + k0 + kq;
      float4 wv = *(const float4*)wp;
      Ws[kq + 0][r] = wv.x; Ws[kq + 1][r] = wv.y; Ws[kq + 2][r] = wv.z; Ws[kq + 3][r] = wv.w;
    }
    __syncthreads();
#pragma unroll
    for (int kk = 0; kk < 16; kk++) {
      float a[8], b[8];
      *(float4*)&a[0] = *(const float4*)&As[kk][ty * 8];
      *(float4*)&a[4] = *(const float4*)&As[kk][ty * 8 + 4];
      *(float4*)&b[0] = *(const float4*)&Ws[kk][tx * 8];
      *(float4*)&b[4] = *(const float4*)&Ws[kk][tx * 8 + 4];
#pragma unroll
      for (int i = 0; i < 8; i++)
#pragma unroll
        for (int j = 0; j < 8; j++) acc[i][j] = fmaf(a[i], b[j], acc[i][j]);
    }
    __syncthreads();
  }
#pragma unroll
  for (int i = 0; i < 8; i++) {
    int m = m0 + ty * 8 + i;
    float* cp = C + (long)m * H_ + n0 + tx * 8;
#pragma unroll
    for (int jq = 0; jq < 2; jq++) {
      int n = n0 + tx * 8 + jq * 4;
      float4 o;
      o.x = acc[i][jq * 4 + 0] + bih[n + 0] + bhh[n + 0];
      o.y = acc[i][jq * 4 + 1] + bih[n + 1] + bhh[n + 1];
      o.z = acc[i][jq * 4 + 2] + bih[n + 2] + bhh[n + 2];
      o.w = acc[i][jq * 4 + 3] + bih[n + 3] + bhh[n + 3];
      *(float4*)(cp + jq * 4) = o;
    }
  }
}

// ---------------------------------------------------------------------------
// Persistent-per-chunk scan. 256 blocks = 64 batches x 4 col-slices(128 cols).
// 512 threads: ks = tid&31 (k-chunk of 16), cg = tid>>5 (8-col group).
// W_hh slice in 128 VGPRs/thread. h exchanged through global hbuf (parity
// double-buffered) with ONE monotonic flag per batch (4 producers).
// y overwrites xp in place (same wave, read-before-write in lockstep).
// Layer 2 fuses the O=1 head (block partial + atomicAdd) and writes no y.
// ---------------------------------------------------------------------------
__global__ __launch_bounds__(512, 2) void rnn_scan(
    float* __restrict__ xp,            // [B][TC][H] chunk (in/out)
    int write_y, int is_last,
    const float* __restrict__ w_hh,    // [H][H]
    float* __restrict__ hbuf,          // this layer: 2*BH floats
    unsigned* __restrict__ flags,      // this layer: 64 counters
    float* __restrict__ hT,            // d_out + MTOT + l*BH
    const float* __restrict__ fc_w,
    const float* __restrict__ fc_b,
    float* __restrict__ outh,          // d_out head part [B][T_]
    int t0) {
  const int tid = threadIdx.x;
  const int b = blockIdx.x >> 2, q = blockIdx.x & 3;
  const int ks = tid & 31, cg = tid >> 5;
  const int k0 = ks * 16;
  const int c0 = q * 128 + cg * 8;
  unsigned* flag = flags + b;

  // W_hh[c0..c0+8, k0..k0+16] -> registers (step-invariant)
  float w[8][16];
#pragma unroll
  for (int j = 0; j < 8; j++) {
    const float* wp = w_hh + (long)(c0 + j) * H_ + k0;
#pragma unroll
    for (int v = 0; v < 4; v++) {
      float4 t4 = *(const float4*)(wp + v * 4);
      w[j][v * 4 + 0] = t4.x; w[j][v * 4 + 1] = t4.y;
      w[j][v * 4 + 2] = t4.z; w[j][v * 4 + 3] = t4.w;
    }
  }
  float fw[8];
  if (is_last) {
#pragma unroll
    for (int j = 0; j < 8; j++) fw[j] = fc_w[c0 + j];
  }
  __shared__ float hp[16];

  for (int trel = 0; trel < TC; trel++) {
    const int t = t0 + trel;
    // xp prefetch (chunk-local, independent of the flag)
    float* xpp = xp + ((long)b * TC + trel) * H_ + c0;
    float4 x0 = *(const float4*)xpp;
    float4 x1 = *(const float4*)(xpp + 4);

    // wait until all 4 producers published h(t-1)
    if (tid == 0) {
      unsigned target = 4u * (unsigned)t;
      while (__hip_atomic_load(flag, __ATOMIC_ACQUIRE, __HIP_MEMORY_SCOPE_AGENT) < target)
        __builtin_amdgcn_s_sleep(1);
    }
    __syncthreads();

    // h(t-1)[b, k0..k0+16]
    const float* hr = hbuf + (long)((t & 1) ^ 1) * BH + (long)b * H_ + k0;
    float4 h0 = *(const float4*)hr;
    float4 h1 = *(const float4*)(hr + 4);
    float4 h2 = *(const float4*)(hr + 8);
    float4 h3 = *(const float4*)(hr + 12);
    float hk[16];
    hk[0] = h0.x; hk[1] = h0.y; hk[2] = h0.z; hk[3] = h0.w;
    hk[4] = h1.x; hk[5] = h1.y; hk[6] = h1.z; hk[7] = h1.w;
    hk[8] = h2.x; hk[9] = h2.y; hk[10] = h2.z; hk[11] = h2.w;
    hk[12] = h3.x; hk[13] = h3.y; hk[14] = h3.z; hk[15] = h3.w;

    float acc[8] = {0.f, 0.f, 0.f, 0.f, 0.f, 0.f, 0.f, 0.f};
#pragma unroll
    for (int kk = 0; kk < 16; kk++)
#pragma unroll
      for (int j = 0; j < 8; j++) acc[j] = fmaf(hk[kk], w[j][kk], acc[j]);

    // butterfly over the 32 ks-lanes (stays within each wave half)
#pragma unroll
    for (int m = 1; m < 32; m <<= 1)
#pragma unroll
      for (int j = 0; j < 8; j++) acc[j] += __shfl_xor(acc[j], m, 64);

    float hv[8];
    hv[0] = fast_tanh(acc[0] + x0.x); hv[1] = fast_tanh(acc[1] + x0.y);
    hv[2] = fast_tanh(acc[2] + x0.z); hv[3] = fast_tanh(acc[3] + x0.w);
    hv[4] = fast_tanh(acc[4] + x1.x); hv[5] = fast_tanh(acc[5] + x1.y);
    hv[6] = fast_tanh(acc[6] + x1.z); hv[7] = fast_tanh(acc[7] + x1.w);

    if (ks == 0) {
      float4 o0 = make_float4(hv[0], hv[1], hv[2], hv[3]);
      float4 o1 = make_float4(hv[4], hv[5], hv[6], hv[7]);
      float* hw = hbuf + (long)(t & 1) * BH + (long)b * H_ + c0;
      *(float4*)hw = o0; *(float4*)(hw + 4) = o1;
      if (write_y) { *(float4*)xpp = o0; *(float4*)(xpp + 4) = o1; }
      if (t == T_ - 1) {
        float* hp2 = hT + (long)b * H_ + c0;
        *(float4*)hp2 = o0; *(float4*)(hp2 + 4) = o1;
      }
      if (is_last) {
        float p = 0.f;
#pragma unroll
        for (int j = 0; j < 8; j++) p = fmaf(hv[j], fw[j], p);
        hp[cg] = p;
      }
    }
    __syncthreads();  // drains all global stores (vmcnt) + publishes hp
    if (tid == 0) {
      if (is_last) {
        float s = 0.f;
#pragma unroll
        for (int i = 0; i < 16; i++) s += hp[i];
        if (q == 0) s += fc_b[0];
        atomicAdd(outh + (long)b * T_ + t, s);
      }
      __threadfence();
      __hip_atomic_fetch_add(flag, 1u, __ATOMIC_RELEASE, __HIP_MEMORY_SCOPE_AGENT);
    }
  }
}

// ---------------------------------------------------------------------------
extern "C" void kernel_launch(void* const* d_in, const int* in_sizes, int n_in,
                              void* d_out, int out_size, void* d_ws, size_t ws_size,
                              hipStream_t stream) {
  const float* input  = (const float*)d_in[0];
  const float* hidden = (const float*)d_in[1];
  const float* w_ih0 = (const float*)d_in[2];
  const float* w_hh0 = (const float*)d_in[3];
  const float* b_ih0 = (const float*)d_in[4];
  const float* b_hh0 = (const float*)d_in[5];
  const float* w_ih1 = (const float*)d_in[6];
  const float* w_hh1 = (const float*)d_in[7];
  const float* b_ih1 = (const float*)d_in[8];
  const float* b_hh1 = (const float*)d_in[9];
  const float* w_ih2 = (const float*)d_in[10];
  const float* w_hh2 = (const float*)d_in[11];
  const float* b_ih2 = (const float*)d_in[12];
  const float* b_hh2 = (const float*)d_in[13];
  const float* fc_w  = (const float*)d_in[14];
  const float* fc_b  = (const float*)d_in[15];

  float* out = (float*)d_out;          // [B,T,1] then h_finals [3,B,H]
  float* hT  = out + MTOT;

  char* ws = (char*)d_ws;
  unsigned* flags = (unsigned*)ws;                  // 192 u32
  float* hbuf = (float*)(ws + 4096);                // 3*2*BH floats (~768 KB)
  float* bufA = (float*)(ws + (1 << 20));           // 32 MB
  float* bufB = bufA + (size_t)MC * H_;             // 32 MB  (total ~66 MB)

  hipMemsetAsync(out, 0, (size_t)MTOT * sizeof(float), stream);
  init_kernel<<<dim3(384), dim3(256), 0, stream>>>(hidden, hbuf, flags);

  dim3 gthr(256), ggrid(H_ / 128, MC / 128);        // (4, 128)
  dim3 sthr(512), sgrid(256);

  for (int c = 0; c < NCHUNK; c++) {
    int t0 = c * TC;
    // layer 0: xp0 = input_chunk @ Wih0^T + biases -> bufA; scan in place
    gemm_xp<<<ggrid, gthr, 0, stream>>>(input + (long)t0 * I_, (long)T_ * I_, I_,
                                        w_ih0, b_ih0, b_hh0, bufA);
    rnn_scan<<<sgrid, sthr, 0, stream>>>(bufA, 1, 0, w_hh0, hbuf + 0 * 2 * BH,
                                         flags + 0, hT + 0 * BH, fc_w, fc_b, out, t0);
    // layer 1
    gemm_xp<<<ggrid, gthr, 0, stream>>>(bufA, (long)TC * H_, H_,
                                        w_ih1, b_ih1, b_hh1, bufB);
    rnn_scan<<<sgrid, sthr, 0, stream>>>(bufB, 1, 0, w_hh1, hbuf + 1 * 2 * BH,
                                         flags + 64, hT + 1 * BH, fc_w, fc_b, out, t0);
    // layer 2 (head fused; no y written)
    gemm_xp<<<ggrid, gthr, 0, stream>>>(bufB, (long)TC * H_, H_,
                                        w_ih2, b_ih2, b_hh2, bufA);
    rnn_scan<<<sgrid, sthr, 0, stream>>>(bufA, 0, 1, w_hh2, hbuf + 2 * 2 * BH,
                                         flags + 128, hT + 2 * BH, fc_w, fc_b, out, t0);
  }
}

// Round 4
// 8410.639 us; speedup vs baseline: 5.7239x; 5.7239x over previous
//
#include <hip/hip_runtime.h>
#include <cstddef>

#define B_ 64
#define T_ 1024
#define I_ 64
#define H_ 512
#define TC 256                  // time-chunk length
#define NCHUNK (T_ / TC)        // 4
#define MTOT (B_ * T_)          // 65536
#define BH (B_ * H_)            // 32768
#define MC (B_ * TC)            // 16384 rows per chunk GEMM

typedef unsigned long long u64;

// ---------------------------------------------------------------------------
// fast tanh: tanh(x) = 1 - 2/(exp2(2*log2e*x)+1). ~1e-6 abs error.
// ---------------------------------------------------------------------------
__device__ __forceinline__ float fast_tanh(float x) {
  float e = __builtin_amdgcn_exp2f(2.885390081777927f * x);
  float r = __builtin_amdgcn_rcpf(e + 1.0f);
  return 1.0f - 2.0f * r;
}

__device__ __forceinline__ u64 pack_h(float h, unsigned tag) {
  return ((u64)tag << 32) | (u64)__float_as_uint(h);
}

// ---------------------------------------------------------------------------
// init: h(-1) -> hx parity-1 slots, tag 0, for all 3 layers.
// hx layout per layer: [2][B*H] u64 words.
// ---------------------------------------------------------------------------
__global__ __launch_bounds__(256) void init_kernel(const float* __restrict__ hidden,
                                                   u64* __restrict__ hx) {
  int idx = blockIdx.x * 256 + threadIdx.x;   // 0 .. 3*BH-1
  int l = idx / BH, r = idx - l * BH;
  u64 w = pack_h(hidden[idx], 0u);
  __hip_atomic_store(&hx[((size_t)l * 2 + 1) * BH + r], w,
                     __ATOMIC_RELAXED, __HIP_MEMORY_SCOPE_AGENT);
}

// ---------------------------------------------------------------------------
// C[m, 0..511] = A[m, :K] @ W[:, :K]^T + bih + bhh.   (unchanged from r3)
// ---------------------------------------------------------------------------
__global__ __launch_bounds__(256) void gemm_xp(const float* __restrict__ A, long bstride, int K,
                                               const float* __restrict__ W,
                                               const float* __restrict__ bih,
                                               const float* __restrict__ bhh,
                                               float* __restrict__ C) {
  __shared__ float As[16][132];
  __shared__ float Ws[16][132];
  const int tid = threadIdx.x;
  const int m0 = blockIdx.y * 128, n0 = blockIdx.x * 128;
  const int tx = tid & 15, ty = tid >> 4;
  float acc[8][8] = {};
  for (int k0 = 0; k0 < K; k0 += 16) {
#pragma unroll
    for (int i = 0; i < 2; i++) {
      int idx = i * 256 + tid;
      int r = idx >> 2, kq = (idx & 3) * 4;
      int row = m0 + r;
      const float* ap = A + (long)(row >> 8) * bstride + (long)(row & 255) * K + k0 + kq;
      float4 av = *(const float4*)ap;
      As[kq + 0][r] = av.x; As[kq + 1][r] = av.y; As[kq + 2][r] = av.z; As[kq + 3][r] = av.w;
      const float* wp = W + (long)(n0 + r) * K + k0 + kq;
      float4 wv = *(const float4*)wp;
      Ws[kq + 0][r] = wv.x; Ws[kq + 1][r] = wv.y; Ws[kq + 2][r] = wv.z; Ws[kq + 3][r] = wv.w;
    }
    __syncthreads();
#pragma unroll
    for (int kk = 0; kk < 16; kk++) {
      float a[8], b[8];
      *(float4*)&a[0] = *(const float4*)&As[kk][ty * 8];
      *(float4*)&a[4] = *(const float4*)&As[kk][ty * 8 + 4];
      *(float4*)&b[0] = *(const float4*)&Ws[kk][tx * 8];
      *(float4*)&b[4] = *(const float4*)&Ws[kk][tx * 8 + 4];
#pragma unroll
      for (int i = 0; i < 8; i++)
#pragma unroll
        for (int j = 0; j < 8; j++) acc[i][j] = fmaf(a[i], b[j], acc[i][j]);
    }
    __syncthreads();
  }
#pragma unroll
  for (int i = 0; i < 8; i++) {
    int m = m0 + ty * 8 + i;
    float* cp = C + (long)m * H_ + n0 + tx * 8;
#pragma unroll
    for (int jq = 0; jq < 2; jq++) {
      int n = n0 + tx * 8 + jq * 4;
      float4 o;
      o.x = acc[i][jq * 4 + 0] + bih[n + 0] + bhh[n + 0];
      o.y = acc[i][jq * 4 + 1] + bih[n + 1] + bhh[n + 1];
      o.z = acc[i][jq * 4 + 2] + bih[n + 2] + bhh[n + 2];
      o.w = acc[i][jq * 4 + 3] + bih[n + 3] + bhh[n + 3];
      *(float4*)(cp + jq * 4) = o;
    }
  }
}

// ---------------------------------------------------------------------------
// Persistent-per-chunk scan with TAGGED-WORD exchange (no fences, no flags).
// 256 blocks = 64 batches x 4 col-slices(128). 512 thr: ks=tid&31, cg=tid>>5.
// W_hh slice in 128 regs/thread. h published as {tag,float} u64 via RELAXED
// agent atomics (sc0 sc1 cache-bypass: coherent, no wbl2/inv). Each thread
// polls exactly one word, stages it to LDS (double-buffered, +1/16 padding),
// then reads its 16-float fragment. One __syncthreads per step.
// Layer 2 fuses the O=1 head; y overwrite of xp is wave-local (race-free).
// ---------------------------------------------------------------------------
__global__ __launch_bounds__(512, 2) void rnn_scan(
    float* __restrict__ xp,            // [B][TC][H] chunk (in/out)
    int write_y, int is_last,
    const float* __restrict__ w_hh,    // [H][H]
    u64* __restrict__ hx,              // this layer: [2][B*H] tagged words
    float* __restrict__ hT,            // d_out + MTOT + l*BH
    const float* __restrict__ fc_w,
    const float* __restrict__ fc_b,
    float* __restrict__ outh,          // d_out head part [B][T_]
    int t0) {
  const int tid = threadIdx.x;
  const int b = blockIdx.x >> 2, q = blockIdx.x & 3;
  const int ks = tid & 31, cg = tid >> 5;
  const int k0 = ks * 16;
  const int c0 = q * 128 + cg * 8;

  // W_hh[c0..c0+8, k0..k0+16] -> registers (step-invariant)
  float w[8][16];
#pragma unroll
  for (int j = 0; j < 8; j++) {
    const float* wp = w_hh + (long)(c0 + j) * H_ + k0;
#pragma unroll
    for (int v = 0; v < 4; v++) {
      float4 t4 = *(const float4*)(wp + v * 4);
      w[j][v * 4 + 0] = t4.x; w[j][v * 4 + 1] = t4.y;
      w[j][v * 4 + 2] = t4.z; w[j][v * 4 + 3] = t4.w;
    }
  }
  float fw[8];
  if (is_last) {
#pragma unroll
    for (int j = 0; j < 8; j++) fw[j] = fc_w[c0 + j];
  }
  __shared__ float h_lds[2][544];   // padded: word k -> k + (k>>4)
  __shared__ float hp[16];

  // my single poll word: h[b, tid] of the previous step
  u64* poll_base = hx + (size_t)b * H_ + tid;

  for (int trel = 0; trel < TC; trel++) {
    const int t = t0 + trel;
    const int p = trel & 1;

    // xp prefetch (chunk-local, independent of exchange)
    float* xpp = xp + ((long)b * TC + trel) * H_ + c0;
    float4 x0 = *(const float4*)xpp;
    float4 x1 = *(const float4*)(xpp + 4);

    // poll my word of h(t-1): slot parity of (t-1), expected tag == t
    {
      u64* pw = poll_base + (size_t)((t & 1) ^ 1) * BH;
      u64 wv = __hip_atomic_load(pw, __ATOMIC_RELAXED, __HIP_MEMORY_SCOPE_AGENT);
      while ((unsigned)(wv >> 32) != (unsigned)t) {
        __builtin_amdgcn_s_sleep(1);
        wv = __hip_atomic_load(pw, __ATOMIC_RELAXED, __HIP_MEMORY_SCOPE_AGENT);
      }
      h_lds[p][tid + (tid >> 4)] = __uint_as_float((unsigned)wv);
    }
    __syncthreads();

    // hk[16] = h(t-1)[b, k0..k0+16] from LDS (conflict-free scalar reads)
    float hk[16];
    {
      const float* hl = &h_lds[p][k0 + ks];   // k0 + (k0>>4) = ks*17
#pragma unroll
      for (int kk = 0; kk < 16; kk++) hk[kk] = hl[kk];
    }

    float acc[8] = {0.f, 0.f, 0.f, 0.f, 0.f, 0.f, 0.f, 0.f};
#pragma unroll
    for (int kk = 0; kk < 16; kk++)
#pragma unroll
      for (int j = 0; j < 8; j++) acc[j] = fmaf(hk[kk], w[j][kk], acc[j]);

    // butterfly over the 32 ks-lanes (lane = (cg&1)*32 + ks; masks<32 stay put)
#pragma unroll
    for (int m = 1; m < 32; m <<= 1)
#pragma unroll
      for (int j = 0; j < 8; j++) acc[j] += __shfl_xor(acc[j], m, 64);

    float hv[8];
    hv[0] = fast_tanh(acc[0] + x0.x); hv[1] = fast_tanh(acc[1] + x0.y);
    hv[2] = fast_tanh(acc[2] + x0.z); hv[3] = fast_tanh(acc[3] + x0.w);
    hv[4] = fast_tanh(acc[4] + x1.x); hv[5] = fast_tanh(acc[5] + x1.y);
    hv[6] = fast_tanh(acc[6] + x1.z); hv[7] = fast_tanh(acc[7] + x1.w);

    // publish h(t): lanes ks<8 write col c0+ks tagged t+1 (slot parity t)
    if (ks < 8) {
      u64 wv = pack_h(hv[ks], (unsigned)(t + 1));
      __hip_atomic_store(hx + (size_t)(t & 1) * BH + (size_t)b * H_ + c0 + ks, wv,
                         __ATOMIC_RELAXED, __HIP_MEMORY_SCOPE_AGENT);
    }

    if (ks == 0) {
      float4 o0 = make_float4(hv[0], hv[1], hv[2], hv[3]);
      float4 o1 = make_float4(hv[4], hv[5], hv[6], hv[7]);
      if (write_y) { *(float4*)xpp = o0; *(float4*)(xpp + 4) = o1; }
      if (t == T_ - 1) {
        float* hp2 = hT + (long)b * H_ + c0;
        *(float4*)hp2 = o0; *(float4*)(hp2 + 4) = o1;
      }
      if (is_last) {
        float pacc = 0.f;
#pragma unroll
        for (int j = 0; j < 8; j++) pacc = fmaf(hv[j], fw[j], pacc);
        hp[cg] = pacc;
      }
    }
    if (is_last) {
      __syncthreads();
      if (tid == 0) {
        float s = 0.f;
#pragma unroll
        for (int i = 0; i < 16; i++) s += hp[i];
        if (q == 0) s += fc_b[0];
        atomicAdd(outh + (long)b * T_ + t, s);
      }
    }
  }
}

// ---------------------------------------------------------------------------
extern "C" void kernel_launch(void* const* d_in, const int* in_sizes, int n_in,
                              void* d_out, int out_size, void* d_ws, size_t ws_size,
                              hipStream_t stream) {
  const float* input  = (const float*)d_in[0];
  const float* hidden = (const float*)d_in[1];
  const float* w_ih0 = (const float*)d_in[2];
  const float* w_hh0 = (const float*)d_in[3];
  const float* b_ih0 = (const float*)d_in[4];
  const float* b_hh0 = (const float*)d_in[5];
  const float* w_ih1 = (const float*)d_in[6];
  const float* w_hh1 = (const float*)d_in[7];
  const float* b_ih1 = (const float*)d_in[8];
  const float* b_hh1 = (const float*)d_in[9];
  const float* w_ih2 = (const float*)d_in[10];
  const float* w_hh2 = (const float*)d_in[11];
  const float* b_ih2 = (const float*)d_in[12];
  const float* b_hh2 = (const float*)d_in[13];
  const float* fc_w  = (const float*)d_in[14];
  const float* fc_b  = (const float*)d_in[15];

  float* out = (float*)d_out;          // [B,T,1] then h_finals [3,B,H]
  float* hT  = out + MTOT;

  char* ws = (char*)d_ws;
  u64* hx = (u64*)ws;                               // 3 layers * 2*BH u64 = 1.5 MB
  float* bufA = (float*)(ws + (4 << 20));           // 32 MB
  float* bufB = bufA + (size_t)MC * H_;             // 32 MB  (total ~68 MB)

  hipMemsetAsync(out, 0, (size_t)MTOT * sizeof(float), stream);
  init_kernel<<<dim3(384), dim3(256), 0, stream>>>(hidden, hx);

  dim3 gthr(256), ggrid(H_ / 128, MC / 128);        // (4, 128)
  dim3 sthr(512), sgrid(256);

  const size_t HX = 2 * (size_t)BH;                 // u64 per layer

  for (int c = 0; c < NCHUNK; c++) {
    int t0 = c * TC;
    // layer 0
    gemm_xp<<<ggrid, gthr, 0, stream>>>(input + (long)t0 * I_, (long)T_ * I_, I_,
                                        w_ih0, b_ih0, b_hh0, bufA);
    rnn_scan<<<sgrid, sthr, 0, stream>>>(bufA, 1, 0, w_hh0, hx + 0 * HX,
                                         hT + 0 * BH, fc_w, fc_b, out, t0);
    // layer 1
    gemm_xp<<<ggrid, gthr, 0, stream>>>(bufA, (long)TC * H_, H_,
                                        w_ih1, b_ih1, b_hh1, bufB);
    rnn_scan<<<sgrid, sthr, 0, stream>>>(bufB, 1, 0, w_hh1, hx + 1 * HX,
                                         hT + 1 * BH, fc_w, fc_b, out, t0);
    // layer 2 (head fused; no y written)
    gemm_xp<<<ggrid, gthr, 0, stream>>>(bufB, (long)TC * H_, H_,
                                        w_ih2, b_ih2, b_hh2, bufA);
    rnn_scan<<<sgrid, sthr, 0, stream>>>(bufA, 0, 1, w_hh2, hx + 2 * HX,
                                         hT + 2 * BH, fc_w, fc_b, out, t0);
  }
}

// Round 11
// 8349.282 us; speedup vs baseline: 5.7660x; 1.0073x over previous
//
#include <hip/hip_runtime.h>
#include <cstddef>

#define B_ 64
#define T_ 1024
#define I_ 64
#define H_ 512
#define TC 256                  // time-chunk length
#define NCHUNK (T_ / TC)        // 4
#define MTOT (B_ * T_)          // 65536
#define BH (B_ * H_)            // 32768
#define MC (B_ * TC)            // 16384 rows per chunk GEMM

typedef unsigned long long u64;
typedef float f2 __attribute__((ext_vector_type(2)));

__device__ __forceinline__ f2 pk_fma(f2 a, f2 b, f2 c) {
#if __has_builtin(__builtin_elementwise_fma)
  return __builtin_elementwise_fma(a, b, c);   // -> v_pk_fma_f32
#else
  f2 r; r.x = fmaf(a.x, b.x, c.x); r.y = fmaf(a.y, b.y, c.y); return r;
#endif
}

// ---------------------------------------------------------------------------
// fast tanh: tanh(x) = 1 - 2/(exp2(2*log2e*x)+1). ~1e-6 abs error.
// ---------------------------------------------------------------------------
__device__ __forceinline__ float fast_tanh(float x) {
  float e = __builtin_amdgcn_exp2f(2.885390081777927f * x);
  float r = __builtin_amdgcn_rcpf(e + 1.0f);
  return 1.0f - 2.0f * r;
}

__device__ __forceinline__ u64 pack_h(float h, unsigned tag) {
  return ((u64)tag << 32) | (u64)__float_as_uint(h);
}

// ---------------------------------------------------------------------------
// init: h(-1) -> hx parity-1 slots, tag 0, for all 3 layers.
// ---------------------------------------------------------------------------
__global__ __launch_bounds__(256) void init_kernel(const float* __restrict__ hidden,
                                                   u64* __restrict__ hx) {
  int idx = blockIdx.x * 256 + threadIdx.x;   // 0 .. 3*BH-1
  int l = idx / BH, r = idx - l * BH;
  u64 w = pack_h(hidden[idx], 0u);
  __hip_atomic_store(&hx[((size_t)l * 2 + 1) * BH + r], w,
                     __ATOMIC_RELAXED, __HIP_MEMORY_SCOPE_AGENT);
}

// ---------------------------------------------------------------------------
// C[m, 0..511] = A[m, :K] @ W[:, :K]^T + bih + bhh.   (unchanged)
// ---------------------------------------------------------------------------
__global__ __launch_bounds__(256) void gemm_xp(const float* __restrict__ A, long bstride, int K,
                                               const float* __restrict__ W,
                                               const float* __restrict__ bih,
                                               const float* __restrict__ bhh,
                                               float* __restrict__ C) {
  __shared__ float As[16][132];
  __shared__ float Ws[16][132];
  const int tid = threadIdx.x;
  const int m0 = blockIdx.y * 128, n0 = blockIdx.x * 128;
  const int tx = tid & 15, ty = tid >> 4;
  float acc[8][8] = {};
  for (int k0 = 0; k0 < K; k0 += 16) {
#pragma unroll
    for (int i = 0; i < 2; i++) {
      int idx = i * 256 + tid;
      int r = idx >> 2, kq = (idx & 3) * 4;
      int row = m0 + r;
      const float* ap = A + (long)(row >> 8) * bstride + (long)(row & 255) * K + k0 + kq;
      float4 av = *(const float4*)ap;
      As[kq + 0][r] = av.x; As[kq + 1][r] = av.y; As[kq + 2][r] = av.z; As[kq + 3][r] = av.w;
      const float* wp = W + (long)(n0 + r) * K + k0 + kq;
      float4 wv = *(const float4*)wp;
      Ws[kq + 0][r] = wv.x; Ws[kq + 1][r] = wv.y; Ws[kq + 2][r] = wv.z; Ws[kq + 3][r] = wv.w;
    }
    __syncthreads();
#pragma unroll
    for (int kk = 0; kk < 16; kk++) {
      float a[8], b[8];
      *(float4*)&a[0] = *(const float4*)&As[kk][ty * 8];
      *(float4*)&a[4] = *(const float4*)&As[kk][ty * 8 + 4];
      *(float4*)&b[0] = *(const float4*)&Ws[kk][tx * 8];
      *(float4*)&b[4] = *(const float4*)&Ws[kk][tx * 8 + 4];
#pragma unroll
      for (int i = 0; i < 8; i++)
#pragma unroll
        for (int j = 0; j < 8; j++) acc[i][j] = fmaf(a[i], b[j], acc[i][j]);
    }
    __syncthreads();
  }
#pragma unroll
  for (int i = 0; i < 8; i++) {
    int m = m0 + ty * 8 + i;
    float* cp = C + (long)m * H_ + n0 + tx * 8;
#pragma unroll
    for (int jq = 0; jq < 2; jq++) {
      int n = n0 + tx * 8 + jq * 4;
      float4 o;
      o.x = acc[i][jq * 4 + 0] + bih[n + 0] + bhh[n + 0];
      o.y = acc[i][jq * 4 + 1] + bih[n + 1] + bhh[n + 1];
      o.z = acc[i][jq * 4 + 2] + bih[n + 2] + bhh[n + 2];
      o.w = acc[i][jq * 4 + 3] + bih[n + 3] + bhh[n + 3];
      *(float4*)(cp + jq * 4) = o;
    }
  }
}

// ---------------------------------------------------------------------------
// Persistent-per-chunk scan, tagged-word exchange (relaxed agent atomics).
// 256 blocks (1/CU guaranteed) = 64 batches x 4 col-slices(128 cols).
// 1024 thr: cg = tid>>5 (32 groups x 4 cols), ks = tid&31 (16-k chunk).
// Per thread: W_hh[4 cols][16 k] = 64 fp32 regs (fits true VGPR, no AGPR),
// 32 v_pk_fma_f32 per step. Threads 0..511 poll one tagged word each ->
// LDS (pad 2/16, b64-aligned). Butterfly over 32 ks-lanes. One barrier/step.
// Layer 2 fuses the O=1 head.
// ---------------------------------------------------------------------------
__global__ __launch_bounds__(1024, 4) void rnn_scan(
    float* __restrict__ xp,            // [B][TC][H] chunk (in/out)
    int write_y, int is_last,
    const float* __restrict__ w_hh,    // [H][H]
    u64* __restrict__ hx,              // this layer: [2][B*H] tagged words
    float* __restrict__ hT,            // d_out + MTOT + l*BH
    const float* __restrict__ fc_w,
    const float* __restrict__ fc_b,
    float* __restrict__ outh,          // d_out head part [B][T_]
    int t0) {
  const int tid = threadIdx.x;
  const int b = blockIdx.x >> 2, q = blockIdx.x & 3;
  const int ks = tid & 31, cg = tid >> 5;
  const int k0 = ks * 16;
  const int c0 = q * 128 + cg * 4;

  // W_hh[c0..c0+4, k0..k0+16] -> 32 f2 regs (step-invariant)
  f2 w2[4][8];
#pragma unroll
  for (int j = 0; j < 4; j++) {
    const f2* wp2 = (const f2*)(w_hh + (long)(c0 + j) * H_ + k0);
#pragma unroll
    for (int i = 0; i < 8; i++) w2[j][i] = wp2[i];
  }
  float fw[4];
  if (is_last) {
#pragma unroll
    for (int j = 0; j < 4; j++) fw[j] = fc_w[c0 + j];
  }

  __shared__ float h_lds[2][576];   // word i stored at i + (i>>4)*2
  __shared__ float hp[32];

  u64* poll_base = hx + (size_t)b * H_ + tid;   // valid for tid<512

  for (int trel = 0; trel < TC; trel++) {
    const int t = t0 + trel;
    const int p = trel & 1;

    // xp prefetch: 4 cols of this cg (same float4 across the 32 ks lanes)
    float* xpp = xp + ((long)b * TC + trel) * H_ + c0;
    float4 x4 = *(const float4*)xpp;

    // poll my word of h(t-1) (tid<512): slot parity of (t-1), tag == t
    if (tid < 512) {
      u64* pw = poll_base + (size_t)((t & 1) ^ 1) * BH;
      u64 wv = __hip_atomic_load(pw, __ATOMIC_RELAXED, __HIP_MEMORY_SCOPE_AGENT);
      while ((unsigned)(wv >> 32) != (unsigned)t) {
        __builtin_amdgcn_s_sleep(1);
        wv = __hip_atomic_load(pw, __ATOMIC_RELAXED, __HIP_MEMORY_SCOPE_AGENT);
      }
      h_lds[p][tid + (tid >> 4) * 2] = __uint_as_float((unsigned)wv);
    }
    __syncthreads();

    // hk2[8] = h(t-1)[b, k0..k0+16] as f2 (base word 18*ks, 8B aligned)
    f2 hk2[8];
    {
      const f2* hl = (const f2*)&h_lds[p][ks * 18];
#pragma unroll
      for (int i = 0; i < 8; i++) hk2[i] = hl[i];
    }

    f2 acc2[4];
#pragma unroll
    for (int j = 0; j < 4; j++) acc2[j] = (f2){0.f, 0.f};
#pragma unroll
    for (int i = 0; i < 8; i++)
#pragma unroll
      for (int j = 0; j < 4; j++) acc2[j] = pk_fma(hk2[i], w2[j][i], acc2[j]);

    float acc[4];
#pragma unroll
    for (int j = 0; j < 4; j++) acc[j] = acc2[j].x + acc2[j].y;

    // butterfly over the 32 ks-lanes (xor masks <32 stay within wave halves)
#pragma unroll
    for (int m = 1; m < 32; m <<= 1)
#pragma unroll
      for (int j = 0; j < 4; j++) acc[j] += __shfl_xor(acc[j], m, 64);

    float hv[4];
    hv[0] = fast_tanh(acc[0] + x4.x);
    hv[1] = fast_tanh(acc[1] + x4.y);
    hv[2] = fast_tanh(acc[2] + x4.z);
    hv[3] = fast_tanh(acc[3] + x4.w);

    // publish h(t): lanes ks<4 store col c0+ks, tag t+1, slot parity t
    if (ks < 4) {
      u64 wv = pack_h(hv[ks], (unsigned)(t + 1));
      __hip_atomic_store(hx + (size_t)(t & 1) * BH + (size_t)b * H_ + c0 + ks, wv,
                         __ATOMIC_RELAXED, __HIP_MEMORY_SCOPE_AGENT);
    }

    if (ks == 0) {
      float4 o = make_float4(hv[0], hv[1], hv[2], hv[3]);
      if (write_y) *(float4*)xpp = o;
      if (t == T_ - 1) *(float4*)(hT + (long)b * H_ + c0) = o;
      if (is_last) {
        float pa = 0.f;
#pragma unroll
        for (int j = 0; j < 4; j++) pa = fmaf(hv[j], fw[j], pa);
        hp[cg] = pa;
      }
    }
    if (is_last) {
      __syncthreads();
      if (tid == 0) {
        float s = 0.f;
#pragma unroll
        for (int i = 0; i < 32; i++) s += hp[i];
        if (q == 0) s += fc_b[0];
        atomicAdd(outh + (long)b * T_ + t, s);
      }
    }
  }
}

// ---------------------------------------------------------------------------
extern "C" void kernel_launch(void* const* d_in, const int* in_sizes, int n_in,
                              void* d_out, int out_size, void* d_ws, size_t ws_size,
                              hipStream_t stream) {
  const float* input  = (const float*)d_in[0];
  const float* hidden = (const float*)d_in[1];
  const float* w_ih0 = (const float*)d_in[2];
  const float* w_hh0 = (const float*)d_in[3];
  const float* b_ih0 = (const float*)d_in[4];
  const float* b_hh0 = (const float*)d_in[5];
  const float* w_ih1 = (const float*)d_in[6];
  const float* w_hh1 = (const float*)d_in[7];
  const float* b_ih1 = (const float*)d_in[8];
  const float* b_hh1 = (const float*)d_in[9];
  const float* w_ih2 = (const float*)d_in[10];
  const float* w_hh2 = (const float*)d_in[11];
  const float* b_ih2 = (const float*)d_in[12];
  const float* b_hh2 = (const float*)d_in[13];
  const float* fc_w  = (const float*)d_in[14];
  const float* fc_b  = (const float*)d_in[15];

  float* out = (float*)d_out;          // [B,T,1] then h_finals [3,B,H]
  float* hT  = out + MTOT;

  char* ws = (char*)d_ws;
  u64* hx = (u64*)ws;                               // 3 * 2*BH u64 = 1.5 MB
  float* bufA = (float*)(ws + (4 << 20));           // 32 MB
  float* bufB = bufA + (size_t)MC * H_;             // 32 MB  (total ~68 MB)

  hipMemsetAsync(out, 0, (size_t)MTOT * sizeof(float), stream);
  init_kernel<<<dim3(384), dim3(256), 0, stream>>>(hidden, hx);

  dim3 gthr(256), ggrid(H_ / 128, MC / 128);        // (4, 128)
  dim3 sthr(1024), sgrid(256);

  const size_t HX = 2 * (size_t)BH;                 // u64 per layer

  for (int c = 0; c < NCHUNK; c++) {
    int t0 = c * TC;
    // layer 0
    gemm_xp<<<ggrid, gthr, 0, stream>>>(input + (long)t0 * I_, (long)T_ * I_, I_,
                                        w_ih0, b_ih0, b_hh0, bufA);
    rnn_scan<<<sgrid, sthr, 0, stream>>>(bufA, 1, 0, w_hh0, hx + 0 * HX,
                                         hT + 0 * BH, fc_w, fc_b, out, t0);
    // layer 1
    gemm_xp<<<ggrid, gthr, 0, stream>>>(bufA, (long)TC * H_, H_,
                                        w_ih1, b_ih1, b_hh1, bufB);
    rnn_scan<<<sgrid, sthr, 0, stream>>>(bufB, 1, 0, w_hh1, hx + 1 * HX,
                                         hT + 1 * BH, fc_w, fc_b, out, t0);
    // layer 2 (head fused; no y written)
    gemm_xp<<<ggrid, gthr, 0, stream>>>(bufB, (long)TC * H_, H_,
                                        w_ih2, b_ih2, b_hh2, bufA);
    rnn_scan<<<sgrid, sthr, 0, stream>>>(bufA, 0, 1, w_hh2, hx + 2 * HX,
                                         hT + 2 * BH, fc_w, fc_b, out, t0);
  }
}